// Round 2
// baseline (4197.884 us; speedup 1.0000x reference)
//
#include <hip/hip_runtime.h>

#define NROWS 32768
#define KCB   8192
#define DDIM  512
#define MT 64
#define KT 128
#define DC 32

// ---------------------------------------------------------------------------
// Kernel 1: row squared-norms, bit-replicating numpy pairwise summation.
// numpy add.reduce over 512 contiguous f32: pairwise split 512->256->128,
// each 128-block: 8 accumulators, 16 sequential adds each, then
// ((r0+r1)+(r2+r3))+((r4+r5)+(r6+r7)); blocks combined (B0+B1)+(B2+B3).
// 32 lanes per row: lane = blk*8 + j owns accumulator j of block blk.
// ---------------------------------------------------------------------------
__global__ __launch_bounds__(256) void sq_pairwise_kernel(
    const float* __restrict__ z, const float* __restrict__ cb,
    float* __restrict__ zsq, float* __restrict__ esq)
{
#pragma clang fp contract(off)
  int gtid = blockIdx.x * 256 + threadIdx.x;
  int row  = gtid >> 5;          // 32 lanes per row
  int l    = threadIdx.x & 31;
  if (row >= NROWS + KCB) return;
  const float* src = (row < NROWS) ? (z + (size_t)row * DDIM)
                                   : (cb + (size_t)(row - NROWS) * DDIM);
  int blk = l >> 3, j = l & 7;
  const float* p = src + blk * 128 + j;
  float acc = 0.0f;
#pragma unroll
  for (int t = 0; t < 16; ++t) {
    float v = p[8 * t];
    float q = v * v;            // numpy squares (z*z temp) round before summing
    acc = acc + q;
  }
  // tree combine of the 8 accumulators (order matches numpy exactly)
  float s = acc + __shfl_xor(acc, 1);
  s = s + __shfl_xor(s, 2);
  s = s + __shfl_xor(s, 4);
  // lanes l=0,8,16,24 now hold B0..B3 at their group base
  float u = s + __shfl_xor(s, 8);    // lane0: B0+B1
  u = u + __shfl_xor(u, 16);         // lane0: (B0+B1)+(B2+B3)
  if (l == 0) {
    if (row < NROWS) zsq[row] = u;
    else             esq[row - NROWS] = u;
  }
}

// ---------------------------------------------------------------------------
// Kernel 2: fused S = z.e^T tile GEMM + argmin + gather epilogue + loss.
// Block: 64 rows x full K loop (k-tiles of 128), d streamed in chunks of 32.
// Thread (ty,tx) 16x16: 4 rows x 8 codes register tile (32 accs).
// Distance replicates numpy: d = fl(fl(zsq+esq) - fl(2*S)); argmin is
// lexicographic (val, idx) == numpy first-index tie-break.
// ---------------------------------------------------------------------------
__global__ __launch_bounds__(256) void vq_main_kernel(
    const float* __restrict__ z, const float* __restrict__ cb,
    const float* __restrict__ zsq, const float* __restrict__ esq,
    float* __restrict__ out_zq, float* __restrict__ out_idx,
    double* __restrict__ loss_acc)
{
  __shared__ float As[DC][68];    // d-major, pad to 68 (16B-aligned rows)
  __shared__ float Bs[DC][140];   // d-major, col swizzled: col' = col + 4*(col>>5)
  __shared__ int   idx_sh[MT];
  __shared__ double red_sh[4];

  const int tid  = threadIdx.x;
  const int row0 = blockIdx.x * MT;
  const int ty = tid >> 4;              // 0..15 -> 4 rows each
  const int tx = tid & 15;              // 0..15 -> 8 codes each

  // staging assignments
  const int arow = tid >> 2;            // 0..63
  const int adof = (tid & 3) << 3;      // 0,8,16,24
  const int brow = tid >> 1;            // 0..127
  const int bdof = (tid & 1) << 4;      // 0,16
  const int bcolw = brow + ((brow >> 5) << 2);        // swizzled store col
  const int bcolr = (tx << 3) + ((tx >> 2) << 2);     // swizzled read col base

  float zs[4];
#pragma unroll
  for (int i = 0; i < 4; ++i) zs[i] = zsq[row0 + (ty << 2) + i];

  float bvbest[4]; int bibest[4];
#pragma unroll
  for (int i = 0; i < 4; ++i) { bvbest[i] = 3.402823466e38f; bibest[i] = 0x7fffffff; }

  for (int k0 = 0; k0 < KCB; k0 += KT) {
    float acc[4][8];
#pragma unroll
    for (int i = 0; i < 4; ++i)
#pragma unroll
      for (int jj = 0; jj < 8; ++jj) acc[i][jj] = 0.0f;

    for (int d0 = 0; d0 < DDIM; d0 += DC) {
      // issue global loads before the barrier (hide latency)
      const float4* ag = (const float4*)(z + (size_t)(row0 + arow) * DDIM + d0 + adof);
      float4 a0 = ag[0];
      float4 a1 = ag[1];
      const float4* bg = (const float4*)(cb + (size_t)(k0 + brow) * DDIM + d0 + bdof);
      float4 b0 = bg[0], b1 = bg[1], b2 = bg[2], b3 = bg[3];
      __syncthreads();   // previous chunk's LDS reads done
      As[adof + 0][arow] = a0.x; As[adof + 1][arow] = a0.y;
      As[adof + 2][arow] = a0.z; As[adof + 3][arow] = a0.w;
      As[adof + 4][arow] = a1.x; As[adof + 5][arow] = a1.y;
      As[adof + 6][arow] = a1.z; As[adof + 7][arow] = a1.w;
      Bs[bdof +  0][bcolw] = b0.x; Bs[bdof +  1][bcolw] = b0.y;
      Bs[bdof +  2][bcolw] = b0.z; Bs[bdof +  3][bcolw] = b0.w;
      Bs[bdof +  4][bcolw] = b1.x; Bs[bdof +  5][bcolw] = b1.y;
      Bs[bdof +  6][bcolw] = b1.z; Bs[bdof +  7][bcolw] = b1.w;
      Bs[bdof +  8][bcolw] = b2.x; Bs[bdof +  9][bcolw] = b2.y;
      Bs[bdof + 10][bcolw] = b2.z; Bs[bdof + 11][bcolw] = b2.w;
      Bs[bdof + 12][bcolw] = b3.x; Bs[bdof + 13][bcolw] = b3.y;
      Bs[bdof + 14][bcolw] = b3.z; Bs[bdof + 15][bcolw] = b3.w;
      __syncthreads();
#pragma unroll 8
      for (int dc = 0; dc < DC; ++dc) {
        float4 a4 = *(const float4*)&As[dc][ty << 2];
        float4 p0 = *(const float4*)&Bs[dc][bcolr];
        float4 p1 = *(const float4*)&Bs[dc][bcolr + 4];
        float av[4] = {a4.x, a4.y, a4.z, a4.w};
        float bw[8] = {p0.x, p0.y, p0.z, p0.w, p1.x, p1.y, p1.z, p1.w};
#pragma unroll
        for (int i = 0; i < 4; ++i)
#pragma unroll
          for (int jj = 0; jj < 8; ++jj)
            acc[i][jj] += av[i] * bw[jj];
      }
    }

    // per-k-tile argmin epilogue (registers only)
    float ek[8];
#pragma unroll
    for (int jj = 0; jj < 8; ++jj) ek[jj] = esq[k0 + (tx << 3) + jj];
#pragma unroll
    for (int i = 0; i < 4; ++i) {
      float cv = 3.402823466e38f; int ci = 0x7fffffff;
#pragma unroll
      for (int jj = 0; jj < 8; ++jj) {
        int k = k0 + (tx << 3) + jj;
        float t1 = zs[i] + ek[jj];          // fl(z_sq + e_sq), as numpy
        float dist = t1 - 2.0f * acc[i][jj]; // fl(t1 - 2S); 2S exact in fp32
        if (dist < cv || (dist == cv && k < ci)) { cv = dist; ci = k; }
      }
#pragma unroll
      for (int off = 1; off < 16; off <<= 1) {  // reduce across the 16 tx lanes
        float ov = __shfl_xor(cv, off);
        int   oi = __shfl_xor(ci, off);
        if (ov < cv || (ov == cv && oi < ci)) { cv = ov; ci = oi; }
      }
      if (cv < bvbest[i] || (cv == bvbest[i] && ci < bibest[i])) {
        bvbest[i] = cv; bibest[i] = ci;
      }
    }
  }

  if (tx == 0) {
#pragma unroll
    for (int i = 0; i < 4; ++i) idx_sh[(ty << 2) + i] = bibest[i];
  }
  __syncthreads();

  // cooperative epilogue: z_q_st = fl(z + fl(c - z)) (bitwise numpy), loss in f64
  double lsum = 0.0;
  for (int t4 = tid; t4 < MT * (DDIM / 4); t4 += 256) {
    int r   = t4 >> 7;          // 128 float4 per row
    int c4  = t4 & 127;
    int grow = row0 + r;
    int kidx = idx_sh[r];
    float4 zv  = *(const float4*)(z  + (size_t)grow * DDIM + (c4 << 2));
    float4 cv4 = *(const float4*)(cb + (size_t)kidx * DDIM + (c4 << 2));
    float t0 = cv4.x - zv.x;
    float t1 = cv4.y - zv.y;
    float t2 = cv4.z - zv.z;
    float t3 = cv4.w - zv.w;
    float4 o;
    o.x = zv.x + t0; o.y = zv.y + t1; o.z = zv.z + t2; o.w = zv.w + t3;
    *(float4*)(out_zq + (size_t)grow * DDIM + (c4 << 2)) = o;
    lsum += (double)t0 * t0 + (double)t1 * t1 + (double)t2 * t2 + (double)t3 * t3;
  }
#pragma unroll
  for (int off = 32; off >= 1; off >>= 1) lsum += __shfl_xor(lsum, off);
  if ((tid & 63) == 0) red_sh[tid >> 6] = lsum;
  __syncthreads();
  if (tid == 0) {
    double s = (red_sh[0] + red_sh[1]) + (red_sh[2] + red_sh[3]);
    atomicAdd(loss_acc, s);
  }

  if (tid < MT) out_idx[row0 + tid] = (float)idx_sh[tid];
}

// ---------------------------------------------------------------------------
// Kernel 3: finalize scalar losses. commitment = 0.25*codebook_loss exactly
// (squares are bitwise equal in the reference).
// ---------------------------------------------------------------------------
__global__ void vq_finalize_kernel(const double* __restrict__ loss_acc,
                                   float* __restrict__ out_sc)
{
  double m = loss_acc[0] * (1.0 / 16777216.0);   // 2^-24, exact scale
  float mf = (float)m;
  out_sc[0] = mf;
  out_sc[1] = 0.25f * mf;
}

extern "C" void kernel_launch(void* const* d_in, const int* in_sizes, int n_in,
                              void* d_out, int out_size, void* d_ws, size_t ws_size,
                              hipStream_t stream)
{
  const float* z  = (const float*)d_in[0];
  const float* cb = (const float*)d_in[1];
  float* out     = (float*)d_out;
  float* out_zq  = out;                                   // 32768*512
  float* out_idx = out + (size_t)NROWS * DDIM;            // 32768 (as float)
  float* out_sc  = out_idx + NROWS;                       // 2 scalars

  double* acc = (double*)d_ws;                            // 8B loss accumulator
  float* zsq = (float*)((char*)d_ws + 256);               // 32768 f32
  float* esq = zsq + NROWS;                               // 8192 f32

  hipMemsetAsync(d_ws, 0, 8, stream);                     // zero loss accumulator
  hipLaunchKernelGGL(sq_pairwise_kernel, dim3((NROWS + KCB) / 8), dim3(256), 0, stream,
                     z, cb, zsq, esq);
  hipLaunchKernelGGL(vq_main_kernel, dim3(NROWS / MT), dim3(256), 0, stream,
                     z, cb, zsq, esq, out_zq, out_idx, acc);
  hipLaunchKernelGGL(vq_finalize_kernel, dim3(1), dim3(1), 0, stream, acc, out_sc);
}

// Round 4
// 849.477 us; speedup vs baseline: 4.9417x; 4.9417x over previous
//
#include <hip/hip_runtime.h>

#define NROWS 32768
#define KCB   8192
#define DDIM  512
#define MT 64
#define KT 128
#define DC 32
#define CAP 32
#define MARGIN 4.88e-4f

typedef short bf16x8 __attribute__((ext_vector_type(8)));
typedef float f32x4  __attribute__((ext_vector_type(4)));

// RNE f32 -> bf16 bits
static __device__ __forceinline__ unsigned short f2bf(float f) {
  unsigned u = __float_as_uint(f);
  return (unsigned short)((u + 0x7fffu + ((u >> 16) & 1u)) >> 16);
}

// Exact sequential-FMA dot over d=0..511 (BLAS k-order, bit-matching ref)
static __device__ __forceinline__ float exact_dot(const float* __restrict__ zp,
                                                  const float* __restrict__ ep) {
  float a = 0.f;
#pragma unroll 8
  for (int d = 0; d < DDIM; d += 4) {
    float4 zv = *(const float4*)(zp + d);
    float4 ev = *(const float4*)(ep + d);
    a = fmaf(zv.x, ev.x, a);
    a = fmaf(zv.y, ev.y, a);
    a = fmaf(zv.z, ev.z, a);
    a = fmaf(zv.w, ev.w, a);
  }
  return a;
}

// ---------------------------------------------------------------------------
// Kernel 1: row squared-norms, bit-replicating numpy pairwise summation.
// (validated round 2: absmax 0)
// ---------------------------------------------------------------------------
__global__ __launch_bounds__(256) void sq_pairwise_kernel(
    const float* __restrict__ z, const float* __restrict__ cb,
    float* __restrict__ zsq, float* __restrict__ esq)
{
#pragma clang fp contract(off)
  int gtid = blockIdx.x * 256 + threadIdx.x;
  int row  = gtid >> 5;
  int l    = threadIdx.x & 31;
  if (row >= NROWS + KCB) return;
  const float* src = (row < NROWS) ? (z + (size_t)row * DDIM)
                                   : (cb + (size_t)(row - NROWS) * DDIM);
  int blk = l >> 3, j = l & 7;
  const float* p = src + blk * 128 + j;
  float acc = 0.0f;
#pragma unroll
  for (int t = 0; t < 16; ++t) {
    float v = p[8 * t];
    float q = v * v;
    acc = acc + q;
  }
  float s = acc + __shfl_xor(acc, 1);
  s = s + __shfl_xor(s, 2);
  s = s + __shfl_xor(s, 4);
  float u = s + __shfl_xor(s, 8);
  u = u + __shfl_xor(u, 16);
  if (l == 0) {
    if (row < NROWS) zsq[row] = u;
    else             esq[row - NROWS] = u;
  }
}

// ---------------------------------------------------------------------------
// Kernel cvt: codebook f32 -> bf16 (RNE) into workspace, once.
// ---------------------------------------------------------------------------
__global__ __launch_bounds__(256) void cvt_cb_kernel(
    const float* __restrict__ cb, unsigned short* __restrict__ cbb)
{
  int t = blockIdx.x * 256 + threadIdx.x;      // 524288 threads, 8 elems each
  const float4* src = (const float4*)(cb + (size_t)t * 8);
  float4 f0 = src[0], f1 = src[1];
  ushort4 o0, o1;
  o0.x = f2bf(f0.x); o0.y = f2bf(f0.y); o0.z = f2bf(f0.z); o0.w = f2bf(f0.w);
  o1.x = f2bf(f1.x); o1.y = f2bf(f1.y); o1.z = f2bf(f1.z); o1.w = f2bf(f1.w);
  *(ushort4*)(cbb + (size_t)t * 8) = o0;
  *(ushort4*)(cbb + (size_t)t * 8 + 4) = o1;
}

// ---------------------------------------------------------------------------
// Kernel 2: MFMA bf16 approx sweep -> candidate collect -> exact rescore.
// Block: 256 thr = 4 waves; 64 rows/block; wave owns 16 rows (A in registers).
// B tile (128 codes x 64 d) bf16 double-buffered in LDS, XOR-swizzled.
// ---------------------------------------------------------------------------
__global__ __launch_bounds__(256) void vq_mfma_kernel(
    const float* __restrict__ z, const float* __restrict__ cb,
    const unsigned short* __restrict__ cbb,
    const float* __restrict__ zsq, const float* __restrict__ esq,
    float* __restrict__ out_zq, float* __restrict__ out_idx,
    double* __restrict__ loss_acc)
{
  __shared__ char BsRaw[2][16384];               // 2 x (128 codes x 64 d x 2B)
  __shared__ int cnt[MT];
  __shared__ int lists[MT][CAP];
  __shared__ unsigned long long bestpk[MT];
  __shared__ double red_sh[4];

  const int tid = threadIdx.x;
  const int l   = tid & 63;
  const int w   = tid >> 6;
  const int row0  = blockIdx.x * MT;
  const int wrow0 = row0 + w * 16;

  for (int i = tid; i < MT; i += 256) { cnt[i] = 0; bestpk[i] = ~0ull; }

  // ---- A fragments: 16 rows x 512 d in registers (bf16), RNE-converted ----
  bf16x8 afrag[16];
  {
    const float* zrow = z + (size_t)(wrow0 + (l & 15)) * DDIM + ((l >> 4) << 3);
#pragma unroll
    for (int c = 0; c < 16; ++c) {
      float4 f0 = *(const float4*)(zrow + c * 32);
      float4 f1 = *(const float4*)(zrow + c * 32 + 4);
      bf16x8 a;
      a[0] = (short)f2bf(f0.x); a[1] = (short)f2bf(f0.y);
      a[2] = (short)f2bf(f0.z); a[3] = (short)f2bf(f0.w);
      a[4] = (short)f2bf(f1.x); a[5] = (short)f2bf(f1.y);
      a[6] = (short)f2bf(f1.z); a[7] = (short)f2bf(f1.w);
      afrag[c] = a;
    }
  }

  float zs_r[4];
#pragma unroll
  for (int r = 0; r < 4; ++r) zs_r[r] = zsq[wrow0 + ((l >> 4) << 2) + r];

  float m_r[4] = {3.4e38f, 3.4e38f, 3.4e38f, 3.4e38f};

  f32x4 acc[8];
#pragma unroll
  for (int nf = 0; nf < 8; ++nf) acc[nf] = (f32x4)0.f;

  // staging: chunk ci -> k0=(ci>>3)*128, d-bytes (ci&7)*128
#define STAGE(BUF, CI)                                                          \
  {                                                                             \
    int k0s = ((CI) >> 3) * KT;                                                 \
    int d0b = ((CI) & 7) * 128;                                                 \
    _Pragma("unroll")                                                           \
    for (int i = 0; i < 4; ++i) {                                               \
      int slot = i * 256 + tid;                                                 \
      int brow = slot >> 3;                                                     \
      int dgrp = slot & 7;                                                      \
      int4 v = *(const int4*)((const char*)cbb + (size_t)(k0s + brow) * 1024    \
                              + d0b + dgrp * 16);                               \
      int wb = brow * 128 + ((dgrp * 16) ^ ((brow & 7) << 4));                  \
      *(int4*)(&BsRaw[BUF][wb]) = v;                                            \
    }                                                                           \
  }

  __syncthreads();
  STAGE(0, 0)

  const int rbase = (l & 15) * 128;
  const int dsw   = ((l >> 4) << 4);
  const int lxor  = (l & 7) << 4;

  for (int ci = 0; ci < 512; ++ci) {
    __syncthreads();
    if (ci + 1 < 512) STAGE((ci + 1) & 1, ci + 1)
    const char* bufp = &BsRaw[ci & 1][0];
    const int ai = (ci & 7) << 1;
#pragma unroll
    for (int nf = 0; nf < 8; ++nf) {
#pragma unroll
      for (int sub = 0; sub < 2; ++sub) {
        int off = nf * 2048 + rbase + ((sub * 64 + dsw) ^ lxor);
        bf16x8 bfrag = *(const bf16x8*)(bufp + off);
        acc[nf] = __builtin_amdgcn_mfma_f32_16x16x32_bf16(afrag[ai + sub], bfrag,
                                                          acc[nf], 0, 0, 0);
      }
    }

    if ((ci & 7) == 7) {
      // ---- per-k-tile epilogue: approx dist, running min, candidate push ----
      int k0 = (ci >> 3) * KT;
      float eq[8];
#pragma unroll
      for (int nf = 0; nf < 8; ++nf) eq[nf] = esq[k0 + (nf << 4) + (l & 15)];
#pragma unroll
      for (int nf = 0; nf < 8; ++nf)
#pragma unroll
        for (int r = 0; r < 4; ++r)
          acc[nf][r] = (zs_r[r] + eq[nf]) - 2.0f * acc[nf][r];

      float rm[4];
#pragma unroll
      for (int r = 0; r < 4; ++r) {
        float m01 = fminf(fminf(acc[0][r], acc[1][r]), fminf(acc[2][r], acc[3][r]));
        float m23 = fminf(fminf(acc[4][r], acc[5][r]), fminf(acc[6][r], acc[7][r]));
        float v = fminf(m01, m23);
        v = fminf(v, __shfl_xor(v, 1));
        v = fminf(v, __shfl_xor(v, 2));
        v = fminf(v, __shfl_xor(v, 4));
        v = fminf(v, __shfl_xor(v, 8));
        rm[r] = v;
        m_r[r] = fminf(m_r[r], v);
      }
      bool anyq = false;
#pragma unroll
      for (int nf = 0; nf < 8; ++nf)
#pragma unroll
        for (int r = 0; r < 4; ++r)
          anyq |= (acc[nf][r] <= m_r[r] + MARGIN);
      if (__any(anyq)) {
#pragma unroll
        for (int nf = 0; nf < 8; ++nf)
#pragma unroll
          for (int r = 0; r < 4; ++r)
            if (acc[nf][r] <= m_r[r] + MARGIN) {
              int rowloc = (w << 4) + ((l >> 4) << 2) + r;
              int pos = atomicAdd(&cnt[rowloc], 1);
              if (pos < CAP) lists[rowloc][pos] = k0 + (nf << 4) + (l & 15);
            }
      }
#pragma unroll
      for (int nf = 0; nf < 8; ++nf) acc[nf] = (f32x4)0.f;
    }
  }
  __syncthreads();

  // ---- exact rescore of candidates (bit-matching ref numerics) ----
  {
    int r = tid >> 2;
    int grow = row0 + r;
    int c = cnt[r] < CAP ? cnt[r] : CAP;
    const float* zp = z + (size_t)grow * DDIM;
    float zsv = zsq[grow];
    for (int s = tid & 3; s < c; s += 4) {
      int k = lists[r][s];
      float dot = exact_dot(zp, cb + (size_t)k * DDIM);
      float dist = (zsv + esq[k]) - 2.0f * dot;
      unsigned long long pk =
          ((unsigned long long)__float_as_uint(dist) << 32) | (unsigned)k;
      atomicMin(&bestpk[r], pk);
    }
  }
  __syncthreads();

  // ---- overflow fallback: full exact scan for any row with cnt > CAP ----
  for (int r2 = 0; r2 < MT; ++r2) {
    if (cnt[r2] > CAP) {
      int grow = row0 + r2;
      const float* zp = z + (size_t)grow * DDIM;
      float zsv = zsq[grow];
      for (int k = tid; k < KCB; k += 256) {
        float dot = exact_dot(zp, cb + (size_t)k * DDIM);
        float dist = (zsv + esq[k]) - 2.0f * dot;
        unsigned long long pk =
            ((unsigned long long)__float_as_uint(dist) << 32) | (unsigned)k;
        atomicMin(&bestpk[r2], pk);
      }
    }
  }
  __syncthreads();

  // ---- output epilogue: indices, z_q_st, loss (validated round 2) ----
  if (tid < MT) out_idx[row0 + tid] = (float)(unsigned)(bestpk[tid] & 0xffffffffu);

  double lsum = 0.0;
  for (int t4 = tid; t4 < MT * (DDIM / 4); t4 += 256) {
    int r   = t4 >> 7;
    int c4  = t4 & 127;
    int grow = row0 + r;
    int kidx = (int)(unsigned)(bestpk[r] & 0xffffffffu);
    float4 zv  = *(const float4*)(z  + (size_t)grow * DDIM + (c4 << 2));
    float4 cv4 = *(const float4*)(cb + (size_t)kidx * DDIM + (c4 << 2));
    float t0 = cv4.x - zv.x;
    float t1 = cv4.y - zv.y;
    float t2 = cv4.z - zv.z;
    float t3 = cv4.w - zv.w;
    float4 o;
    o.x = zv.x + t0; o.y = zv.y + t1; o.z = zv.z + t2; o.w = zv.w + t3;
    *(float4*)(out_zq + (size_t)grow * DDIM + (c4 << 2)) = o;
    lsum += (double)t0 * t0 + (double)t1 * t1 + (double)t2 * t2 + (double)t3 * t3;
  }
#pragma unroll
  for (int off = 32; off >= 1; off >>= 1) lsum += __shfl_xor(lsum, off);
  if ((tid & 63) == 0) red_sh[tid >> 6] = lsum;
  __syncthreads();
  if (tid == 0) {
    double s = (red_sh[0] + red_sh[1]) + (red_sh[2] + red_sh[3]);
    atomicAdd(loss_acc, s);
  }
}

// ---------------------------------------------------------------------------
// Kernel 2 (FALLBACK, validated round 2): fp32 VALU fused GEMM+argmin.
// Used only if ws_size can't hold the bf16 codebook.
// ---------------------------------------------------------------------------
__global__ __launch_bounds__(256) void vq_main_kernel(
    const float* __restrict__ z, const float* __restrict__ cb,
    const float* __restrict__ zsq, const float* __restrict__ esq,
    float* __restrict__ out_zq, float* __restrict__ out_idx,
    double* __restrict__ loss_acc)
{
  __shared__ float As[DC][68];
  __shared__ float Bs[DC][140];
  __shared__ int   idx_sh[MT];
  __shared__ double red_sh[4];

  const int tid  = threadIdx.x;
  const int row0 = blockIdx.x * MT;
  const int ty = tid >> 4;
  const int tx = tid & 15;

  const int arow = tid >> 2;
  const int adof = (tid & 3) << 3;
  const int brow = tid >> 1;
  const int bdof = (tid & 1) << 4;
  const int bcolw = brow + ((brow >> 5) << 2);
  const int bcolr = (tx << 3) + ((tx >> 2) << 2);

  float zs[4];
#pragma unroll
  for (int i = 0; i < 4; ++i) zs[i] = zsq[row0 + (ty << 2) + i];

  float bvbest[4]; int bibest[4];
#pragma unroll
  for (int i = 0; i < 4; ++i) { bvbest[i] = 3.402823466e38f; bibest[i] = 0x7fffffff; }

  for (int k0 = 0; k0 < KCB; k0 += KT) {
    float acc[4][8];
#pragma unroll
    for (int i = 0; i < 4; ++i)
#pragma unroll
      for (int jj = 0; jj < 8; ++jj) acc[i][jj] = 0.0f;

    for (int d0 = 0; d0 < DDIM; d0 += DC) {
      const float4* ag = (const float4*)(z + (size_t)(row0 + arow) * DDIM + d0 + adof);
      float4 a0 = ag[0];
      float4 a1 = ag[1];
      const float4* bg = (const float4*)(cb + (size_t)(k0 + brow) * DDIM + d0 + bdof);
      float4 b0 = bg[0], b1 = bg[1], b2 = bg[2], b3 = bg[3];
      __syncthreads();
      As[adof + 0][arow] = a0.x; As[adof + 1][arow] = a0.y;
      As[adof + 2][arow] = a0.z; As[adof + 3][arow] = a0.w;
      As[adof + 4][arow] = a1.x; As[adof + 5][arow] = a1.y;
      As[adof + 6][arow] = a1.z; As[adof + 7][arow] = a1.w;
      Bs[bdof +  0][bcolw] = b0.x; Bs[bdof +  1][bcolw] = b0.y;
      Bs[bdof +  2][bcolw] = b0.z; Bs[bdof +  3][bcolw] = b0.w;
      Bs[bdof +  4][bcolw] = b1.x; Bs[bdof +  5][bcolw] = b1.y;
      Bs[bdof +  6][bcolw] = b1.z; Bs[bdof +  7][bcolw] = b1.w;
      Bs[bdof +  8][bcolw] = b2.x; Bs[bdof +  9][bcolw] = b2.y;
      Bs[bdof + 10][bcolw] = b2.z; Bs[bdof + 11][bcolw] = b2.w;
      Bs[bdof + 12][bcolw] = b3.x; Bs[bdof + 13][bcolw] = b3.y;
      Bs[bdof + 14][bcolw] = b3.z; Bs[bdof + 15][bcolw] = b3.w;
      __syncthreads();
#pragma unroll 8
      for (int dc = 0; dc < DC; ++dc) {
        float4 a4 = *(const float4*)&As[dc][ty << 2];
        float4 p0 = *(const float4*)&Bs[dc][bcolr];
        float4 p1 = *(const float4*)&Bs[dc][bcolr + 4];
        float av[4] = {a4.x, a4.y, a4.z, a4.w};
        float bw[8] = {p0.x, p0.y, p0.z, p0.w, p1.x, p1.y, p1.z, p1.w};
#pragma unroll
        for (int i = 0; i < 4; ++i)
#pragma unroll
          for (int jj = 0; jj < 8; ++jj)
            acc[i][jj] += av[i] * bw[jj];
      }
    }

    float ek[8];
#pragma unroll
    for (int jj = 0; jj < 8; ++jj) ek[jj] = esq[k0 + (tx << 3) + jj];
#pragma unroll
    for (int i = 0; i < 4; ++i) {
      float cv = 3.402823466e38f; int ci = 0x7fffffff;
#pragma unroll
      for (int jj = 0; jj < 8; ++jj) {
        int k = k0 + (tx << 3) + jj;
        float t1 = zs[i] + ek[jj];
        float dist = t1 - 2.0f * acc[i][jj];
        if (dist < cv || (dist == cv && k < ci)) { cv = dist; ci = k; }
      }
#pragma unroll
      for (int off = 1; off < 16; off <<= 1) {
        float ov = __shfl_xor(cv, off);
        int   oi = __shfl_xor(ci, off);
        if (ov < cv || (ov == cv && oi < ci)) { cv = ov; ci = oi; }
      }
      if (cv < bvbest[i] || (cv == bvbest[i] && ci < bibest[i])) {
        bvbest[i] = cv; bibest[i] = ci;
      }
    }
  }

  if (tx == 0) {
#pragma unroll
    for (int i = 0; i < 4; ++i) idx_sh[(ty << 2) + i] = bibest[i];
  }
  __syncthreads();

  double lsum = 0.0;
  for (int t4 = tid; t4 < MT * (DDIM / 4); t4 += 256) {
    int r   = t4 >> 7;
    int c4  = t4 & 127;
    int grow = row0 + r;
    int kidx = idx_sh[r];
    float4 zv  = *(const float4*)(z  + (size_t)grow * DDIM + (c4 << 2));
    float4 cv4 = *(const float4*)(cb + (size_t)kidx * DDIM + (c4 << 2));
    float t0 = cv4.x - zv.x;
    float t1 = cv4.y - zv.y;
    float t2 = cv4.z - zv.z;
    float t3 = cv4.w - zv.w;
    float4 o;
    o.x = zv.x + t0; o.y = zv.y + t1; o.z = zv.z + t2; o.w = zv.w + t3;
    *(float4*)(out_zq + (size_t)grow * DDIM + (c4 << 2)) = o;
    lsum += (double)t0 * t0 + (double)t1 * t1 + (double)t2 * t2 + (double)t3 * t3;
  }
#pragma unroll
  for (int off = 32; off >= 1; off >>= 1) lsum += __shfl_xor(lsum, off);
  if ((tid & 63) == 0) red_sh[tid >> 6] = lsum;
  __syncthreads();
  if (tid == 0) {
    double s = (red_sh[0] + red_sh[1]) + (red_sh[2] + red_sh[3]);
    atomicAdd(loss_acc, s);
  }

  if (tid < MT) out_idx[row0 + tid] = (float)idx_sh[tid];
}

// ---------------------------------------------------------------------------
// Kernel 3: finalize scalar losses.
// ---------------------------------------------------------------------------
__global__ void vq_finalize_kernel(const double* __restrict__ loss_acc,
                                   float* __restrict__ out_sc)
{
  double m = loss_acc[0] * (1.0 / 16777216.0);
  float mf = (float)m;
  out_sc[0] = mf;
  out_sc[1] = 0.25f * mf;
}

extern "C" void kernel_launch(void* const* d_in, const int* in_sizes, int n_in,
                              void* d_out, int out_size, void* d_ws, size_t ws_size,
                              hipStream_t stream)
{
  const float* z  = (const float*)d_in[0];
  const float* cb = (const float*)d_in[1];
  float* out     = (float*)d_out;
  float* out_zq  = out;
  float* out_idx = out + (size_t)NROWS * DDIM;
  float* out_sc  = out_idx + NROWS;

  double* acc = (double*)d_ws;
  float* zsq = (float*)((char*)d_ws + 256);
  float* esq = zsq + NROWS;
  unsigned short* cbb = (unsigned short*)((char*)d_ws + (1 << 20));

  hipMemsetAsync(d_ws, 0, 8, stream);
  hipLaunchKernelGGL(sq_pairwise_kernel, dim3((NROWS + KCB) / 8), dim3(256), 0, stream,
                     z, cb, zsq, esq);
  if (ws_size >= (size_t)10 * 1024 * 1024) {
    hipLaunchKernelGGL(cvt_cb_kernel, dim3(KCB * DDIM / 8 / 256), dim3(256), 0, stream,
                       cb, cbb);
    hipLaunchKernelGGL(vq_mfma_kernel, dim3(NROWS / MT), dim3(256), 0, stream,
                       z, cb, cbb, zsq, esq, out_zq, out_idx, acc);
  } else {
    hipLaunchKernelGGL(vq_main_kernel, dim3(NROWS / MT), dim3(256), 0, stream,
                       z, cb, zsq, esq, out_zq, out_idx, acc);
  }
  hipLaunchKernelGGL(vq_finalize_kernel, dim3(1), dim3(1), 0, stream, acc, out_sc);
}